// Round 3
// baseline (377.734 us; speedup 1.0000x reference)
//
#include <hip/hip_runtime.h>
#include <math.h>

#define GD 128  // dynamic/feature dim

// ---------------- dependency-pruning infrastructure ----------------

// Wave-aggregated append: one atomic per wave instead of per lane.
__device__ __forceinline__ int wave_append(int pred, int* __restrict__ cnt) {
    unsigned long long mask = __ballot(pred);
    if (mask == 0ULL) return -1;
    int lane = threadIdx.x & 63;
    int prefix = __popcll(mask & ((1ULL << lane) - 1ULL));
    int leader = __ffsll((long long)mask) - 1;
    int base = 0;
    if (lane == leader) base = atomicAdd(cnt, __popcll(mask));
    base = __shfl(base, leader, 64);
    return pred ? (base + prefix) : -1;
}

__global__ __launch_bounds__(256) void mark_codeids(const int* __restrict__ codeid, int B,
                                                    int* __restrict__ mark) {
    int i = blockIdx.x * 256 + threadIdx.x;
    if (i < B) mark[codeid[i]] = 1;
}

// For each edge e: if markIn[erow[e]] -> append e to list, set markOut[ecol[e]]
__global__ __launch_bounds__(256) void filter_edges(const int* __restrict__ erow,
                                                    const int* __restrict__ ecol, int E,
                                                    const int* __restrict__ markIn,
                                                    int* __restrict__ markOut,
                                                    int* __restrict__ list,
                                                    int* __restrict__ cnt) {
    int e = blockIdx.x * 256 + threadIdx.x;
    int pred = 0;
    if (e < E) pred = markIn[erow[e]];
    if (pred) markOut[ecol[e]] = 1;
    int pos = wave_append(pred, cnt);
    if (pos >= 0) list[pos] = e;
}

__global__ __launch_bounds__(256) void compact_rows(const int* __restrict__ mark0,
                                                    const int* __restrict__ mark1, int N,
                                                    int* __restrict__ rows0, int* __restrict__ cnt0,
                                                    int* __restrict__ rows1, int* __restrict__ cnt1) {
    int r = blockIdx.x * 256 + threadIdx.x;
    int p0 = (r < N) ? mark0[r] : 0;
    int p1 = (r < N) ? mark1[r] : 0;
    int pos0 = wave_append(p0, cnt0);
    if (pos0 >= 0) rows0[pos0] = r;
    int pos1 = wave_append(p1, cnt1);
    if (pos1 >= 0) rows1[pos1] = r;
}

// ---------------- compute kernels (grid-stride, device-count driven) ----------------

// Y[rows[i]] = X[rows[i]] @ W for i < *cntp. 8 rows/block-iteration, 32 thr/row.
// In-place safe (X==Y): rows are staged into LDS before any store.
__global__ __launch_bounds__(256) void gemm_rows(const float* __restrict__ X,
                                                 const float* __restrict__ W,
                                                 float* __restrict__ Y,
                                                 const int* __restrict__ rows,
                                                 const int* __restrict__ cntp) {
    __shared__ float xs[8 * GD];
    __shared__ int rid[8];
    int t = threadIdx.x;
    int cnt = *cntp;
    int ngroups = (cnt + 7) >> 3;
    for (int g = blockIdx.x; g < ngroups; g += gridDim.x) {
        if (t < 8) {
            int gi = g * 8 + t;
            rid[t] = (gi < cnt) ? rows[gi] : -1;
        }
        __syncthreads();
        int r = rid[t >> 5];
        if (r >= 0) ((float4*)xs)[t] = ((const float4*)(X + (size_t)r * GD))[t & 31];
        __syncthreads();
        int c4 = (t & 31) * 4;
        const float* xrow = xs + (t >> 5) * GD;
        float a0 = 0.f, a1 = 0.f, a2 = 0.f, a3 = 0.f;
#pragma unroll 8
        for (int k = 0; k < GD; ++k) {
            float xv = xrow[k];
            float4 w = *(const float4*)(W + k * GD + c4);
            a0 += xv * w.x; a1 += xv * w.y; a2 += xv * w.z; a3 += xv * w.w;
        }
        if (r >= 0) *(float4*)(Y + (size_t)r * GD + c4) = make_float4(a0, a1, a2, a3);
        __syncthreads();
    }
}

__global__ __launch_bounds__(256) void zero_rows(float* __restrict__ buf,
                                                 const int* __restrict__ rows,
                                                 const int* __restrict__ cntp) {
    int cnt = *cntp;
    int total = cnt * 32;  // float4 per thread
    for (int i = blockIdx.x * 256 + threadIdx.x; i < total; i += gridDim.x * 256) {
        int r = rows[i >> 5];
        ((float4*)(buf + (size_t)r * GD))[i & 31] = make_float4(0.f, 0.f, 0.f, 0.f);
    }
}

__global__ __launch_bounds__(256) void zero_rows_n(float* __restrict__ buf,
                                                   const int* __restrict__ rows, int n) {
    int total = n * 32;
    for (int i = blockIdx.x * 256 + threadIdx.x; i < total; i += gridDim.x * 256) {
        int r = rows[i >> 5];
        ((float4*)(buf + (size_t)r * GD))[i & 31] = make_float4(0.f, 0.f, 0.f, 0.f);
    }
}

// agg[erow[e]][c] += S[ecol[e]][c] * ev[e] over filtered edge list
__global__ __launch_bounds__(256) void scatter_list(const float* __restrict__ S,
                                                    const int* __restrict__ list,
                                                    const int* __restrict__ cntp,
                                                    const int* __restrict__ erow,
                                                    const int* __restrict__ ecol,
                                                    const float* __restrict__ ev,
                                                    float* __restrict__ agg) {
    int cnt = *cntp;
    long long total = (long long)cnt * GD;
    for (long long i = (long long)blockIdx.x * 256 + threadIdx.x; i < total;
         i += (long long)gridDim.x * 256) {
        int e = list[(int)(i >> 7)];
        int c = (int)(i & 127);
        atomicAdd(agg + (size_t)erow[e] * GD + c, S[(size_t)ecol[e] * GD + c] * ev[e]);
    }
}

// out[rows[i]] = relu(0.1*agg[rows[i]] + 0.9*init[rows[i]])
__global__ __launch_bounds__(256) void blend_rows(const float* __restrict__ agg,
                                                  const float* __restrict__ init,
                                                  float* __restrict__ out,
                                                  const int* __restrict__ rows,
                                                  const int* __restrict__ cntp) {
    int cnt = *cntp;
    int total = cnt * 32;
    for (int i = blockIdx.x * 256 + threadIdx.x; i < total; i += gridDim.x * 256) {
        int r = rows[i >> 5];
        int c = i & 31;
        float4 a = ((const float4*)(agg + (size_t)r * GD))[c];
        float4 b = ((const float4*)(init + (size_t)r * GD))[c];
        float4 o;
        o.x = fmaxf(0.1f * a.x + 0.9f * b.x, 0.0f);
        o.y = fmaxf(0.1f * a.y + 0.9f * b.y, 0.0f);
        o.z = fmaxf(0.1f * a.z + 0.9f * b.z, 0.0f);
        o.w = fmaxf(0.1f * a.w + 0.9f * b.w, 0.0f);
        ((float4*)(out + (size_t)r * GD))[c] = o;
    }
}

// One block (128 threads) per output row b.
__global__ __launch_bounds__(128) void final_rnn(const float* __restrict__ agg2,
                                                 const float* __restrict__ init,
                                                 const float* __restrict__ patient,
                                                 const float* __restrict__ timediffs,
                                                 const float* __restrict__ features,
                                                 const float* __restrict__ W_ih,
                                                 const float* __restrict__ b_ih,
                                                 const float* __restrict__ W_hh,
                                                 const float* __restrict__ b_hh,
                                                 const int* __restrict__ codeid,
                                                 const int* __restrict__ patientid,
                                                 float* __restrict__ out) {
    __shared__ float in1[257];
    __shared__ float ce[GD];
    __shared__ float red[GD];
    int b = blockIdx.x;
    int j = threadIdx.x;
    int cid = codeid[b];
    int pid = patientid[0];

    ce[j] = fmaxf(0.1f * agg2[(size_t)cid * GD + j] + 0.9f * init[(size_t)cid * GD + j], 0.0f);
    in1[j] = patient[(size_t)pid * GD + j];
    in1[GD + 1 + j] = features[(size_t)b * GD + j];
    if (j == 0) in1[GD] = timediffs[b];
    __syncthreads();

    float acc = b_ih[j] + b_hh[j];
    const float* wih = W_ih + (size_t)j * 257;
#pragma unroll 8
    for (int k = 0; k < 257; ++k) acc += in1[k] * wih[k];
    const float* whh = W_hh + (size_t)j * GD;
#pragma unroll 8
    for (int k = 0; k < GD; ++k) acc += ce[k] * whh[k];
    float h = tanhf(acc);

    red[j] = h * h;
    __syncthreads();
    for (int s = 64; s > 0; s >>= 1) {
        if (j < s) red[j] += red[j + s];
        __syncthreads();
    }
    float nrm = fmaxf(sqrtf(red[0]), 1e-12f);
    out[(size_t)b * GD + j] = h / nrm;
}

extern "C" void kernel_launch(void* const* d_in, const int* in_sizes, int n_in,
                              void* d_out, int out_size, void* d_ws, size_t ws_size,
                              hipStream_t stream) {
    const float* code_dynamic = (const float*)d_in[0];
    const float* init_cd      = (const float*)d_in[1];
    const float* patient      = (const float*)d_in[2];
    const float* timediffs    = (const float*)d_in[3];
    const float* features     = (const float*)d_in[4];
    const float* edge_val     = (const float*)d_in[5];
    const float* W1           = (const float*)d_in[6];
    const float* W2           = (const float*)d_in[7];
    const float* W_ih         = (const float*)d_in[8];
    const float* b_ih         = (const float*)d_in[9];
    const float* W_hh         = (const float*)d_in[10];
    const float* b_hh         = (const float*)d_in[11];
    const int* edge_row       = (const int*)d_in[12];
    const int* edge_col       = (const int*)d_in[13];
    const int* codeid         = (const int*)d_in[14];
    const int* patientid      = (const int*)d_in[15];

    int N = in_sizes[0] / GD;   // 60000
    int E = in_sizes[5];        // 600000
    int B = in_sizes[14];       // 256
    size_t nd = (size_t)N * GD;

    // workspace layout
    float* bufA = (float*)d_ws;          // support / x1   (N*128 f32)
    float* bufB = bufA + nd;             // agg            (N*128 f32)
    int* list1  = (int*)(bufB + nd);     // E
    int* list2  = list1 + E;             // E
    int* mark0  = list2 + E;             // N  -- zeroed region starts here
    int* mark1  = mark0 + N;             // N
    int* mark2  = mark1 + N;             // N
    int* rows0  = mark2 + N;             // N
    int* rows1  = rows0 + N;             // N
    int* cnts   = rows1 + N;             // 8 ints: [cntE2, cntE1, cntR0, cntR1]

    hipMemsetAsync(mark0, 0, ((size_t)5 * N + 8) * sizeof(int), stream);

    int eb = (E + 255) / 256;
    int nb = (N + 255) / 256;

    // dependency cone: codeid rows -> edges2 -> needed1 rows -> edges1 -> needed0 rows
    mark_codeids<<<(B + 255) / 256, 256, 0, stream>>>(codeid, B, mark2);
    filter_edges<<<eb, 256, 0, stream>>>(edge_row, edge_col, E, mark2, mark1, list2, &cnts[0]);
    filter_edges<<<eb, 256, 0, stream>>>(edge_row, edge_col, E, mark1, mark0, list1, &cnts[1]);
    compact_rows<<<nb, 256, 0, stream>>>(mark0, mark1, N, rows0, &cnts[2], rows1, &cnts[3]);

    // layer 1 (only needed0 rows / edges1 / needed1 rows)
    gemm_rows<<<1024, 256, 0, stream>>>(code_dynamic, W1, bufA, rows0, &cnts[2]);
    zero_rows<<<256, 256, 0, stream>>>(bufB, rows1, &cnts[3]);
    scatter_list<<<2048, 256, 0, stream>>>(bufA, list1, &cnts[1], edge_row, edge_col, edge_val, bufB);
    blend_rows<<<256, 256, 0, stream>>>(bufB, init_cd, bufA, rows1, &cnts[3]);

    // layer 2 (only needed1 rows / edges2 / codeid rows)
    gemm_rows<<<1024, 256, 0, stream>>>(bufA, W2, bufA, rows1, &cnts[3]);  // in-place safe
    zero_rows_n<<<32, 256, 0, stream>>>(bufB, codeid, B);
    scatter_list<<<2048, 256, 0, stream>>>(bufA, list2, &cnts[0], edge_row, edge_col, edge_val, bufB);

    // RNNCell + L2 normalize
    final_rnn<<<B, 128, 0, stream>>>(bufB, init_cd, patient, timediffs, features,
                                     W_ih, b_ih, W_hh, b_hh, codeid, patientid,
                                     (float*)d_out);
}